// Round 5
// baseline (163.072 us; speedup 1.0000x reference)
//
#include <hip/hip_runtime.h>
#include <stdint.h>

#define Bn 2
#define Tn 2048
#define Cn 1024
#define Hn 16
#define Dn 64
#define Mn (Bn*Tn)

typedef __attribute__((ext_vector_type(8))) short bf16x8;
typedef __attribute__((ext_vector_type(4))) float f32x4;
typedef __attribute__((ext_vector_type(4))) unsigned int u32x4;
typedef __attribute__((ext_vector_type(2))) unsigned int u32x2;
typedef unsigned short u16;

__device__ __forceinline__ u16 f2bf(float f) {
  union { float f; uint32_t u; } v; v.f = f;
  uint32_t u = v.u;
  return (u16)((u + 0x7fffu + ((u >> 16) & 1u)) >> 16);
}

__device__ __forceinline__ uint32_t pk_bf16(float lo, float hi) {
  uint32_t r;
  asm volatile("v_cvt_pk_bf16_f32 %0, %1, %2" : "=v"(r) : "v"(lo), "v"(hi));
  return r;
}

__device__ __forceinline__ void async16(const void* g, void* lds) {
  __builtin_amdgcn_global_load_lds((const __attribute__((address_space(1))) void*)g,
                                   (__attribute__((address_space(3))) void*)lds,
                                   16, 0, 0);
}

// ---------------- conversion kernels ----------------

__global__ void cvt_x(const float* __restrict__ x, u16* __restrict__ xb) {
  int i = (blockIdx.x * 256 + threadIdx.x) * 4;
  float4 v = *(const float4*)(x + i);
  ushort4 o;
  o.x = f2bf(v.x); o.y = f2bf(v.y); o.z = f2bf(v.z); o.w = f2bf(v.w);
  *(ushort4*)(xb + i) = o;
}

// in: [K][N] f32 row-major  ->  out: [N][K] bf16 row-major (transpose + convert)
template<int K, int N>
__global__ void cvt_T(const float* __restrict__ in, u16* __restrict__ out) {
  __shared__ float tile[32][33];
  int n0 = blockIdx.x * 32, k0 = blockIdx.y * 32;
  int tx = threadIdx.x & 31, ty = threadIdx.x >> 5;  // 32 x 8
  #pragma unroll
  for (int i = 0; i < 32; i += 8)
    tile[ty + i][tx] = in[(size_t)(k0 + ty + i) * N + n0 + tx];
  __syncthreads();
  #pragma unroll
  for (int i = 0; i < 32; i += 8)
    out[(size_t)(n0 + ty + i) * K + k0 + tx] = f2bf(tile[tx][ty + i]);
}

// ---------------- GEMM:  C[M,N] = A[M,K=1024] * Bt[N,K]^T  (bf16 in, f32 acc) ----------------

template<int EPI>
__launch_bounds__(256, 2)
__global__ void gemm_bt(const u16* __restrict__ A, const u16* __restrict__ Bt, int N,
                        u16* __restrict__ Qb, u16* __restrict__ Kb, u16* __restrict__ Vb,
                        float* __restrict__ Out, const float* __restrict__ bias) {
  constexpr int Kd = 1024;
  __shared__ u16 As[128][64];
  __shared__ u16 Bs[128][64];
  const int nT = N >> 7;
  const int m0 = (blockIdx.x / nT) << 7;
  const int n0 = (blockIdx.x % nT) << 7;
  const int tid = threadIdx.x;
  const int lane = tid & 63, wid = tid >> 6;
  const int wr = wid >> 1, wc = wid & 1;
  const int lr = lane & 15, lg = lane >> 4;

  f32x4 acc[4][4] = {};

  for (int kb = 0; kb < Kd; kb += 64) {
    #pragma unroll
    for (int i = 0; i < 4; ++i) {
      int c = (wid * 4 + i) * 64 + lane;     // chunk id 0..1023
      int row = c >> 3, ko = (c & 7) << 3;
      async16(A + (size_t)(m0 + row) * Kd + kb + ko, &As[0][0] + c * 8);
      async16(Bt + (size_t)(n0 + row) * Kd + kb + ko, &Bs[0][0] + c * 8);
    }
    __syncthreads();
    bf16x8 af[2][4], bf[2][4];
    #pragma unroll
    for (int kc = 0; kc < 2; ++kc) {
      #pragma unroll
      for (int mi = 0; mi < 4; ++mi) {
        af[kc][mi] = *(const bf16x8*)&As[wr * 64 + mi * 16 + lr][kc * 32 + lg * 8];
        bf[kc][mi] = *(const bf16x8*)&Bs[wc * 64 + mi * 16 + lr][kc * 32 + lg * 8];
      }
    }
    #pragma unroll
    for (int kc = 0; kc < 2; ++kc)
      #pragma unroll
      for (int mi = 0; mi < 4; ++mi)
        #pragma unroll
        for (int ni = 0; ni < 4; ++ni)
          acc[mi][ni] = __builtin_amdgcn_mfma_f32_16x16x32_bf16(af[kc][mi], bf[kc][ni], acc[mi][ni], 0, 0, 0);
    __syncthreads();
  }

  if constexpr (EPI == 0) {
    #pragma unroll
    for (int mi = 0; mi < 4; ++mi) {
      int r0 = m0 + wr * 64 + mi * 16 + lg * 4;   // 4 consecutive rows
      int bb = r0 >> 11;
      int t0 = r0 & 2047;
      #pragma unroll
      for (int ni = 0; ni < 4; ++ni) {
        int col = n0 + wc * 64 + ni * 16 + lr;
        int sel = col >> 10, rem = col & 1023;
        int h = rem >> 6, d = rem & 63;
        f32x4 v = acc[mi][ni];
        if (sel == 0) {
          size_t base = ((size_t)(bb * Hn + h) * Tn + t0) * Dn + d;
          #pragma unroll
          for (int r = 0; r < 4; ++r) Qb[base + (size_t)r * Dn] = f2bf(v[r] * 0.125f);
        } else if (sel == 1) {
          size_t base = ((size_t)(bb * Hn + h) * Tn + t0) * Dn + d;
          #pragma unroll
          for (int r = 0; r < 4; ++r) Kb[base + (size_t)r * Dn] = f2bf(v[r]);
        } else {
          size_t base = ((size_t)(bb * Hn + h) * Dn + d) * Tn + t0;
          ushort4 o;
          o.x = f2bf(v[0]); o.y = f2bf(v[1]); o.z = f2bf(v[2]); o.w = f2bf(v[3]);
          *(ushort4*)(Vb + base) = o;
        }
      }
    }
  } else {
    #pragma unroll
    for (int mi = 0; mi < 4; ++mi) {
      int r0 = m0 + wr * 64 + mi * 16 + lg * 4;
      #pragma unroll
      for (int ni = 0; ni < 4; ++ni) {
        int col = n0 + wc * 64 + ni * 16 + lr;
        float bv = bias[col];
        #pragma unroll
        for (int r = 0; r < 4; ++r)
          Out[(size_t)(r0 + r) * Cn + col] = acc[mi][ni][r] + bv;
      }
    }
  }
}

// ---------------- flash attention v4 ------------------------------------------
// grid: 1024 blocks = 8 XCD x (4 bh-local x 32 q-tiles, longest first).
// 256 thr = 4 waves, each wave owns 16 q rows of one 64-row q-tile.
// K double-buffered in LDS (XOR-swizzled, global_load_lds); V read directly
// from global [D][T] into registers (L2-resident per XCD); P via per-wave LDS.
// S computed as mfma(K,Q): lane holds S[k = f*16+lg*4+r][q = lr].
// PV computed as mfma(V^T, P): O^T[dv = f*16+lg*4+r][q = lr].

__device__ __forceinline__ void stage_k(const u16* __restrict__ K, int k0,
                                        u16* __restrict__ Kbuf, int tid) {
  #pragma unroll
  for (int i = 0; i < 2; ++i) {
    int c = i * 256 + tid;            // chunk 0..511 (16 B each)
    int row = c >> 3;
    int js = (c & 7) ^ (row & 7);     // inverse-swizzled source chunk
    async16(K + (size_t)(k0 + row) * Dn + js * 8, Kbuf + c * 8);
  }
}

__launch_bounds__(256, 4)
__global__ void attn(const u16* __restrict__ Qb, const u16* __restrict__ Kb,
                     const u16* __restrict__ Vb, u16* __restrict__ Ob) {
  __shared__ u16 __attribute__((aligned(16))) Ks[2 * 4096];
  __shared__ uint32_t __attribute__((aligned(16))) P32[4][16][36]; // per-wave [q][d or k]

  const int raw = blockIdx.x;
  const int xcd = raw & 7;
  const int idx = raw >> 3;                 // 0..127
  const int bh  = xcd * 4 + (idx & 3);      // 4 heads per XCD -> L2 locality
  const int qt  = 31 - (idx >> 2);          // longest q-tiles dispatched first
  const int q0  = qt * 64;
  const int nt  = qt + 1;

  const int tid = threadIdx.x;
  const int lane = tid & 63, wid = tid >> 6;
  const int lr = lane & 15, lg = lane >> 4;
  const int bb = bh >> 4, h = bh & 15;

  const u16* Q  = Qb + (size_t)bh * Tn * Dn;
  const u16* K  = Kb + (size_t)bh * Tn * Dn;
  const u16* Vt = Vb + (size_t)bh * Dn * Tn;

  const int swz = (lr & 7);           // read-side XOR key for K tile
  const int qoff = wid * 16 + lr;     // q offset within 64-row q-tile
  const int koff0 = lg * 4;           // k offset base for this lane

  // Q fragments (B operand): rows q0 + qoff
  bf16x8 qf[2];
  qf[0] = *(const bf16x8*)(Q + (size_t)(q0 + qoff) * Dn + lg * 8);
  qf[1] = *(const bf16x8*)(Q + (size_t)(q0 + qoff) * Dn + 32 + lg * 8);

  f32x4 o[4] = {};                    // O^T: o[f][r] = O[dv=f*16+lg*4+r][q=lr]
  float m = -1e30f, l = 0.f;

  int cur = 0;
  stage_k(K, 0, Ks, tid);
  __syncthreads();

  for (int t = 0; t < nt; ++t) {
    const int k0 = t << 6;
    if (t + 1 < nt)
      stage_k(K, (t + 1) << 6, Ks + (cur ^ 1) * 4096, tid);

    // V fragments straight from global (L2): issued early, used in PV
    bf16x8 vf[2][4];
    #pragma unroll
    for (int kc = 0; kc < 2; ++kc)
      #pragma unroll
      for (int f = 0; f < 4; ++f)
        vf[kc][f] = *(const bf16x8*)(Vt + (size_t)(f * 16 + lr) * Tn + k0 + kc * 32 + lg * 8);

    const u16* Kc = Ks + cur * 4096;

    // S^T = K Q^T : s[f][r] = S[k = f*16+lg*4+r][q = lr]
    f32x4 s[4] = {};
    __builtin_amdgcn_s_setprio(1);
    #pragma unroll
    for (int f = 0; f < 4; ++f) {
      const int row = f * 16 + lr;
      #pragma unroll
      for (int kc = 0; kc < 2; ++kc) {
        bf16x8 kf = *(const bf16x8*)(Kc + row * 64 + (((kc * 4 + lg) ^ swz) * 8));
        s[f] = __builtin_amdgcn_mfma_f32_16x16x32_bf16(kf, qf[kc], s[f], 0, 0, 0);
      }
    }
    __builtin_amdgcn_s_setprio(0);

    if (t == nt - 1) {               // diagonal tile: mask k > q
      #pragma unroll
      for (int f = 0; f < 4; ++f)
        #pragma unroll
        for (int r = 0; r < 4; ++r)
          if (f * 16 + koff0 + r > qoff) s[f][r] = -1e30f;
    }

    // per-lane row max over 16 k values, then across the 4 lg groups
    float pm = fmaxf(fmaxf(fmaxf(s[0][0], s[0][1]), fmaxf(s[0][2], s[0][3])),
                     fmaxf(fmaxf(s[1][0], s[1][1]), fmaxf(s[1][2], s[1][3])));
    float pm2 = fmaxf(fmaxf(fmaxf(s[2][0], s[2][1]), fmaxf(s[2][2], s[2][3])),
                      fmaxf(fmaxf(s[3][0], s[3][1]), fmaxf(s[3][2], s[3][3])));
    pm = fmaxf(pm, pm2);
    pm = fmaxf(pm, __shfl_xor(pm, 16));
    pm = fmaxf(pm, __shfl_xor(pm, 32));

    // defer-max: only rescale when the max grew by more than THR=8
    if (!__all(pm - m <= 8.f)) {
      float mn = fmaxf(m, pm);
      float fac = __expf(m - mn);
      l *= fac;
      #pragma unroll
      for (int f = 0; f < 4; ++f) {
        o[f][0] *= fac; o[f][1] *= fac; o[f][2] *= fac; o[f][3] *= fac;
      }
      m = mn;
    }

    float sum = 0.f;
    #pragma unroll
    for (int f = 0; f < 4; ++f) {
      #pragma unroll
      for (int r = 0; r < 4; ++r) {
        float p = __expf(s[f][r] - m);
        s[f][r] = p;
        sum += p;
      }
    }
    sum += __shfl_xor(sum, 16);
    sum += __shfl_xor(sum, 32);
    l += sum;

    // P -> per-wave LDS [q][k], packed b64 writes (4 consecutive k per lane)
    #pragma unroll
    for (int f = 0; f < 4; ++f) {
      u32x2 w;
      w.x = pk_bf16(s[f][0], s[f][1]);
      w.y = pk_bf16(s[f][2], s[f][3]);
      *(u32x2*)&P32[wid][lr][f * 8 + lg * 2] = w;   // u16 offset f*16+lg*4
    }

    // O^T += V^T P : A = V^T fragment (dv rows), B = P fragment ([k][q])
    __builtin_amdgcn_s_setprio(1);
    #pragma unroll
    for (int kc = 0; kc < 2; ++kc) {
      u32x4 p4 = *(const u32x4*)&P32[wid][lr][kc * 16 + lg * 4]; // u16 off kc*32+lg*8
      bf16x8 pf = __builtin_bit_cast(bf16x8, p4);
      #pragma unroll
      for (int f = 0; f < 4; ++f)
        o[f] = __builtin_amdgcn_mfma_f32_16x16x32_bf16(vf[kc][f], pf, o[f], 0, 0, 0);
    }
    __builtin_amdgcn_s_setprio(0);

    __syncthreads();                 // drains vmcnt (stage t+1) + LDS reads done
    cur ^= 1;
  }

  // normalize, transpose O^T -> O via P32, store full rows to [B*T][C]
  float inv = 1.f / l;
  #pragma unroll
  for (int f = 0; f < 4; ++f) {
    u32x2 w;
    w.x = pk_bf16(o[f][0] * inv, o[f][1] * inv);
    w.y = pk_bf16(o[f][2] * inv, o[f][3] * inv);
    *(u32x2*)&P32[wid][lr][f * 8 + lg * 2] = w;     // P32[q=lr][d = f*16+lg*4..+3]
  }
  // each of the 4 lg-lanes sharing q-row lr stores 16 d-values (2 x 16B)
  u32x4 r0 = *(const u32x4*)&P32[wid][lr][lg * 8];       // d = lg*16 .. +7
  u32x4 r1 = *(const u32x4*)&P32[wid][lr][lg * 8 + 4];   // d = lg*16+8 .. +15
  u16* obase = Ob + ((size_t)(bb * Tn + q0 + qoff)) * Cn + h * Dn + lg * 16;
  *(u32x4*)(obase) = r0;
  *(u32x4*)(obase + 8) = r1;
}

// ---------------- launch ----------------

extern "C" void kernel_launch(void* const* d_in, const int* in_sizes, int n_in,
                              void* d_out, int out_size, void* d_ws, size_t ws_size,
                              hipStream_t stream) {
  const float* x = (const float*)d_in[0];
  const float* w_qkv = (const float*)d_in[1];
  const float* w_proj = (const float*)d_in[2];
  const float* b_proj = (const float*)d_in[3];
  float* out = (float*)d_out;
  char* ws = (char*)d_ws;

  u16* xb     = (u16*)(ws);                       // 8 MB (reused as attn_out after gemm1)
  u16* wqkvT  = (u16*)(ws + (size_t)( 8u << 20)); // 6 MB
  u16* wprojT = (u16*)(ws + (size_t)(14u << 20)); // 2 MB
  u16* Qb     = (u16*)(ws + (size_t)(16u << 20)); // 8 MB
  u16* Kb     = (u16*)(ws + (size_t)(24u << 20)); // 8 MB
  u16* Vb     = (u16*)(ws + (size_t)(32u << 20)); // 8 MB  (total 40 MB)

  cvt_x<<<dim3(4096), dim3(256), 0, stream>>>(x, xb);
  cvt_T<1024, 3072><<<dim3(96, 32), dim3(256), 0, stream>>>(w_qkv, wqkvT);
  cvt_T<1024, 1024><<<dim3(32, 32), dim3(256), 0, stream>>>(w_proj, wprojT);

  gemm_bt<0><<<dim3(32 * 24), dim3(256), 0, stream>>>(xb, wqkvT, 3072,
                                                      Qb, Kb, Vb, nullptr, nullptr);
  attn<<<dim3(1024), dim3(256), 0, stream>>>(Qb, Kb, Vb, xb /* attn_out */);
  gemm_bt<1><<<dim3(32 * 8), dim3(256), 0, stream>>>(xb, wprojT, 1024,
                                                     nullptr, nullptr, nullptr, out, b_proj);
}

// Round 6
// 120.828 us; speedup vs baseline: 1.3496x; 1.3496x over previous
//
#include <hip/hip_runtime.h>
#include <stdint.h>

#define Bn 2
#define Tn 2048
#define Cn 1024
#define Hn 16
#define Dn 64
#define Mn (Bn*Tn)

typedef __attribute__((ext_vector_type(8))) short bf16x8;
typedef __attribute__((ext_vector_type(4))) float f32x4;
typedef __attribute__((ext_vector_type(4))) unsigned int u32x4;
typedef __attribute__((ext_vector_type(2))) unsigned int u32x2;
typedef unsigned short u16;

__device__ __forceinline__ u16 f2bf(float f) {
  union { float f; uint32_t u; } v; v.f = f;
  uint32_t u = v.u;
  return (u16)((u + 0x7fffu + ((u >> 16) & 1u)) >> 16);
}

__device__ __forceinline__ uint32_t pk_bf16(float lo, float hi) {
  uint32_t r;
  asm volatile("v_cvt_pk_bf16_f32 %0, %1, %2" : "=v"(r) : "v"(lo), "v"(hi));
  return r;
}

__device__ __forceinline__ void async16(const void* g, void* lds) {
  __builtin_amdgcn_global_load_lds((const __attribute__((address_space(1))) void*)g,
                                   (__attribute__((address_space(3))) void*)lds,
                                   16, 0, 0);
}

// ---------------- conversion kernels ----------------

__global__ void cvt_x(const float* __restrict__ x, u16* __restrict__ xb) {
  int i = (blockIdx.x * 256 + threadIdx.x) * 4;
  float4 v = *(const float4*)(x + i);
  ushort4 o;
  o.x = f2bf(v.x); o.y = f2bf(v.y); o.z = f2bf(v.z); o.w = f2bf(v.w);
  *(ushort4*)(xb + i) = o;
}

// in: [K][N] f32 row-major  ->  out: [N][K] bf16 row-major (transpose + convert)
template<int K, int N>
__global__ void cvt_T(const float* __restrict__ in, u16* __restrict__ out) {
  __shared__ float tile[32][33];
  int n0 = blockIdx.x * 32, k0 = blockIdx.y * 32;
  int tx = threadIdx.x & 31, ty = threadIdx.x >> 5;  // 32 x 8
  #pragma unroll
  for (int i = 0; i < 32; i += 8)
    tile[ty + i][tx] = in[(size_t)(k0 + ty + i) * N + n0 + tx];
  __syncthreads();
  #pragma unroll
  for (int i = 0; i < 32; i += 8)
    out[(size_t)(n0 + ty + i) * K + k0 + tx] = f2bf(tile[tx][ty + i]);
}

// ---------------- GEMM:  C[M,N] = A[M,K=1024] * Bt[N,K]^T  (bf16 in, f32 acc) ----------------
// launch_bounds(256,3): grid for GEMM1 is 768 = 3 blocks/CU -> single dispatch
// round (was 2/CU + 256-block tail). LDS 32KB x3 = 96KB OK.
// XCD-chunked bijective grid swizzle (grid % 8 == 0): same-XCD blocks share
// B-panels in that XCD's L2.

template<int EPI>
__launch_bounds__(256, 3)
__global__ void gemm_bt(const u16* __restrict__ A, const u16* __restrict__ Bt, int N,
                        u16* __restrict__ Qb, u16* __restrict__ Kb, u16* __restrict__ Vb,
                        float* __restrict__ Out, const float* __restrict__ bias) {
  constexpr int Kd = 1024;
  __shared__ u16 As[128][64];
  __shared__ u16 Bs[128][64];
  const int nT = N >> 7;
  const int cpx = gridDim.x >> 3;
  const int wg = (blockIdx.x & 7) * cpx + (blockIdx.x >> 3);   // XCD-chunked
  const int m0 = (wg / nT) << 7;
  const int n0 = (wg % nT) << 7;
  const int tid = threadIdx.x;
  const int lane = tid & 63, wid = tid >> 6;
  const int wr = wid >> 1, wc = wid & 1;
  const int lr = lane & 15, lg = lane >> 4;

  f32x4 acc[4][4] = {};

  for (int kb = 0; kb < Kd; kb += 64) {
    #pragma unroll
    for (int i = 0; i < 4; ++i) {
      int c = (wid * 4 + i) * 64 + lane;     // chunk id 0..1023
      int row = c >> 3, ko = (c & 7) << 3;
      async16(A + (size_t)(m0 + row) * Kd + kb + ko, &As[0][0] + c * 8);
      async16(Bt + (size_t)(n0 + row) * Kd + kb + ko, &Bs[0][0] + c * 8);
    }
    __syncthreads();
    bf16x8 af[2][4], bf[2][4];
    #pragma unroll
    for (int kc = 0; kc < 2; ++kc) {
      #pragma unroll
      for (int mi = 0; mi < 4; ++mi) {
        af[kc][mi] = *(const bf16x8*)&As[wr * 64 + mi * 16 + lr][kc * 32 + lg * 8];
        bf[kc][mi] = *(const bf16x8*)&Bs[wc * 64 + mi * 16 + lr][kc * 32 + lg * 8];
      }
    }
    #pragma unroll
    for (int kc = 0; kc < 2; ++kc)
      #pragma unroll
      for (int mi = 0; mi < 4; ++mi)
        #pragma unroll
        for (int ni = 0; ni < 4; ++ni)
          acc[mi][ni] = __builtin_amdgcn_mfma_f32_16x16x32_bf16(af[kc][mi], bf[kc][ni], acc[mi][ni], 0, 0, 0);
    __syncthreads();
  }

  if constexpr (EPI == 0) {
    #pragma unroll
    for (int mi = 0; mi < 4; ++mi) {
      int r0 = m0 + wr * 64 + mi * 16 + lg * 4;   // 4 consecutive rows
      int bb = r0 >> 11;
      int t0 = r0 & 2047;
      #pragma unroll
      for (int ni = 0; ni < 4; ++ni) {
        int col = n0 + wc * 64 + ni * 16 + lr;
        int sel = col >> 10, rem = col & 1023;
        int h = rem >> 6, d = rem & 63;
        f32x4 v = acc[mi][ni];
        if (sel == 0) {
          size_t base = ((size_t)(bb * Hn + h) * Tn + t0) * Dn + d;
          #pragma unroll
          for (int r = 0; r < 4; ++r) Qb[base + (size_t)r * Dn] = f2bf(v[r] * 0.125f);
        } else if (sel == 1) {
          size_t base = ((size_t)(bb * Hn + h) * Tn + t0) * Dn + d;
          #pragma unroll
          for (int r = 0; r < 4; ++r) Kb[base + (size_t)r * Dn] = f2bf(v[r]);
        } else {
          size_t base = ((size_t)(bb * Hn + h) * Dn + d) * Tn + t0;
          ushort4 o;
          o.x = f2bf(v[0]); o.y = f2bf(v[1]); o.z = f2bf(v[2]); o.w = f2bf(v[3]);
          *(ushort4*)(Vb + base) = o;
        }
      }
    }
  } else {
    #pragma unroll
    for (int mi = 0; mi < 4; ++mi) {
      int r0 = m0 + wr * 64 + mi * 16 + lg * 4;
      #pragma unroll
      for (int ni = 0; ni < 4; ++ni) {
        int col = n0 + wc * 64 + ni * 16 + lr;
        float bv = bias[col];
        #pragma unroll
        for (int r = 0; r < 4; ++r)
          Out[(size_t)(r0 + r) * Cn + col] = acc[mi][ni][r] + bv;
      }
    }
  }
}

// ---------------- flash attention (round-4 proven version) ---------------------
// grid: 512 blocks = 32 bh x 16 pair-slots (XCD-chunked). 256 thr = 4 waves.
// Block handles q-tiles {a, 31-a}: exactly 33 KV tiles each -> uniform work.
// S computed as mfma(K,Q): lane holds S[k = f*16+lg*4+r][q = lr].
// PV computed as mfma(V^T, P): O^T[dv = f*16+lg*4+r][q = lr].

__device__ __forceinline__ void stage_kv(const u16* __restrict__ K,
                                         const u16* __restrict__ Vt, int k0,
                                         u16* __restrict__ Kbuf, u16* __restrict__ Vbuf,
                                         int tid) {
  #pragma unroll
  for (int i = 0; i < 2; ++i) {
    int c = i * 256 + tid;            // chunk 0..511 (16 B each)
    int row = c >> 3;
    int js = (c & 7) ^ (row & 7);     // inverse-swizzled source chunk
    async16(K + (size_t)(k0 + row) * Dn + js * 8, Kbuf + c * 8);
    async16(Vt + (size_t)row * Tn + k0 + js * 8, Vbuf + c * 8);
  }
}

__launch_bounds__(256, 2)
__global__ void attn(const u16* __restrict__ Qb, const u16* __restrict__ Kb,
                     const u16* __restrict__ Vb, u16* __restrict__ Ob) {
  __shared__ u16 __attribute__((aligned(16))) Ks[2 * 4096];
  __shared__ u16 __attribute__((aligned(16))) Vs[2 * 4096];
  __shared__ uint32_t __attribute__((aligned(16))) P32[4][16][36]; // per-wave [q][d or k]

  const int x = blockIdx.x;
  const int wg = (x & 7) * 64 + (x >> 3);       // XCD-chunked (512 % 8 == 0)
  const int bh = wg >> 4;
  const int a  = wg & 15;
  const int tid = threadIdx.x;
  const int lane = tid & 63, wid = tid >> 6;
  const int lr = lane & 15, lg = lane >> 4;
  const int bb = bh >> 4, h = bh & 15;

  const u16* Q  = Qb + (size_t)bh * Tn * Dn;
  const u16* K  = Kb + (size_t)bh * Tn * Dn;
  const u16* Vt = Vb + (size_t)bh * Dn * Tn;

  const int swz = (lr & 7);           // read-side XOR key for K/V tiles
  const int qoff = wid * 16 + lr;     // q offset within 64-row q-tile
  const int koff0 = lg * 4;           // k offset base for this lane

  #pragma unroll 1
  for (int g = 0; g < 2; ++g) {
    const int q0 = (g == 0 ? (31 - a) : a) * 64;   // long tile first
    const int nt = (q0 >> 6) + 1;

    // Q fragments (B operand): rows q0 + qoff
    bf16x8 qf[2];
    qf[0] = *(const bf16x8*)(Q + (size_t)(q0 + qoff) * Dn + lg * 8);
    qf[1] = *(const bf16x8*)(Q + (size_t)(q0 + qoff) * Dn + 32 + lg * 8);

    f32x4 o[4] = {};                   // O^T: o[f][r] = O[dv=f*16+lg*4+r][q=lr]
    float m = -1e30f, l = 0.f;

    int cur = 0;
    stage_kv(K, Vt, 0, Ks, Vs, tid);
    __syncthreads();

    for (int t = 0; t < nt; ++t) {
      if (t + 1 < nt)
        stage_kv(K, Vt, (t + 1) << 6,
                 Ks + (cur ^ 1) * 4096, Vs + (cur ^ 1) * 4096, tid);

      const u16* Kc = Ks + cur * 4096;
      const u16* Vc = Vs + cur * 4096;

      // S^T = K Q^T : s[f][r] = S[k = f*16+lg*4+r][q = lr]
      f32x4 s[4] = {};
      __builtin_amdgcn_s_setprio(1);
      #pragma unroll
      for (int f = 0; f < 4; ++f) {
        const int row = f * 16 + lr;
        #pragma unroll
        for (int kc = 0; kc < 2; ++kc) {
          bf16x8 kf = *(const bf16x8*)(Kc + row * 64 + (((kc * 4 + lg) ^ swz) * 8));
          s[f] = __builtin_amdgcn_mfma_f32_16x16x32_bf16(kf, qf[kc], s[f], 0, 0, 0);
        }
      }
      __builtin_amdgcn_s_setprio(0);

      if (t == nt - 1) {               // diagonal tile: mask k > q
        #pragma unroll
        for (int f = 0; f < 4; ++f)
          #pragma unroll
          for (int r = 0; r < 4; ++r)
            if (f * 16 + koff0 + r > qoff) s[f][r] = -1e30f;
      }

      // per-lane row max over 16 k values, then across the 4 lg groups
      float pm = fmaxf(fmaxf(fmaxf(s[0][0], s[0][1]), fmaxf(s[0][2], s[0][3])),
                       fmaxf(fmaxf(s[1][0], s[1][1]), fmaxf(s[1][2], s[1][3])));
      float pm2 = fmaxf(fmaxf(fmaxf(s[2][0], s[2][1]), fmaxf(s[2][2], s[2][3])),
                        fmaxf(fmaxf(s[3][0], s[3][1]), fmaxf(s[3][2], s[3][3])));
      pm = fmaxf(pm, pm2);
      pm = fmaxf(pm, __shfl_xor(pm, 16));
      pm = fmaxf(pm, __shfl_xor(pm, 32));

      // defer-max: only rescale when the max grew by more than THR=8
      if (!__all(pm - m <= 8.f)) {
        float mn = fmaxf(m, pm);
        float fac = __expf(m - mn);
        l *= fac;
        #pragma unroll
        for (int f = 0; f < 4; ++f) {
          o[f][0] *= fac; o[f][1] *= fac; o[f][2] *= fac; o[f][3] *= fac;
        }
        m = mn;
      }

      float sum = 0.f;
      #pragma unroll
      for (int f = 0; f < 4; ++f) {
        #pragma unroll
        for (int r = 0; r < 4; ++r) {
          float p = __expf(s[f][r] - m);
          s[f][r] = p;
          sum += p;
        }
      }
      sum += __shfl_xor(sum, 16);
      sum += __shfl_xor(sum, 32);
      l += sum;

      // P -> per-wave LDS [q][k], packed b64 writes (4 consecutive k per lane)
      #pragma unroll
      for (int f = 0; f < 4; ++f) {
        u32x2 w;
        w.x = pk_bf16(s[f][0], s[f][1]);
        w.y = pk_bf16(s[f][2], s[f][3]);
        *(u32x2*)&P32[wid][lr][f * 8 + lg * 2] = w;   // u16 offset f*16+lg*4
      }

      // O^T += V^T P : A = V^T fragment (dv rows), B = P fragment ([k][q])
      __builtin_amdgcn_s_setprio(1);
      #pragma unroll
      for (int kc = 0; kc < 2; ++kc) {
        u32x4 p4 = *(const u32x4*)&P32[wid][lr][kc * 16 + lg * 4]; // u16 off kc*32+lg*8
        bf16x8 pf = __builtin_bit_cast(bf16x8, p4);
        #pragma unroll
        for (int f = 0; f < 4; ++f) {
          const int row = f * 16 + lr;
          bf16x8 vf = *(const bf16x8*)(Vc + row * 64 + (((kc * 4 + lg) ^ swz) * 8));
          o[f] = __builtin_amdgcn_mfma_f32_16x16x32_bf16(vf, pf, o[f], 0, 0, 0);
        }
      }
      __builtin_amdgcn_s_setprio(0);

      __syncthreads();                 // drains vmcnt (stage t+1) + LDS reads done
      cur ^= 1;
    }

    // normalize, transpose O^T -> O via P32, store full rows to [B*T][C]
    float inv = 1.f / l;
    #pragma unroll
    for (int f = 0; f < 4; ++f) {
      u32x2 w;
      w.x = pk_bf16(o[f][0] * inv, o[f][1] * inv);
      w.y = pk_bf16(o[f][2] * inv, o[f][3] * inv);
      *(u32x2*)&P32[wid][lr][f * 8 + lg * 2] = w;     // P32[q=lr][d = f*16+lg*4..+3]
    }
    // each of the 4 lg-lanes sharing q-row lr stores 16 d-values (2 x 16B)
    u32x4 r0 = *(const u32x4*)&P32[wid][lr][lg * 8];       // d = lg*16 .. +7
    u32x4 r1 = *(const u32x4*)&P32[wid][lr][lg * 8 + 4];   // d = lg*16+8 .. +15
    u16* obase = Ob + ((size_t)(bb * Tn + q0 + qoff)) * Cn + h * Dn + lg * 16;
    *(u32x4*)(obase) = r0;
    *(u32x4*)(obase + 8) = r1;
    __syncthreads();                   // group A done before group B restages
  }
}

// ---------------- launch ----------------

extern "C" void kernel_launch(void* const* d_in, const int* in_sizes, int n_in,
                              void* d_out, int out_size, void* d_ws, size_t ws_size,
                              hipStream_t stream) {
  const float* x = (const float*)d_in[0];
  const float* w_qkv = (const float*)d_in[1];
  const float* w_proj = (const float*)d_in[2];
  const float* b_proj = (const float*)d_in[3];
  float* out = (float*)d_out;
  char* ws = (char*)d_ws;

  u16* xb     = (u16*)(ws);                       // 8 MB (reused as attn_out after gemm1)
  u16* wqkvT  = (u16*)(ws + (size_t)( 8u << 20)); // 6 MB
  u16* wprojT = (u16*)(ws + (size_t)(14u << 20)); // 2 MB
  u16* Qb     = (u16*)(ws + (size_t)(16u << 20)); // 8 MB
  u16* Kb     = (u16*)(ws + (size_t)(24u << 20)); // 8 MB
  u16* Vb     = (u16*)(ws + (size_t)(32u << 20)); // 8 MB  (total 40 MB)

  cvt_x<<<dim3(4096), dim3(256), 0, stream>>>(x, xb);
  cvt_T<1024, 3072><<<dim3(96, 32), dim3(256), 0, stream>>>(w_qkv, wqkvT);
  cvt_T<1024, 1024><<<dim3(32, 32), dim3(256), 0, stream>>>(w_proj, wprojT);

  gemm_bt<0><<<dim3(32 * 24), dim3(256), 0, stream>>>(xb, wqkvT, 3072,
                                                      Qb, Kb, Vb, nullptr, nullptr);
  attn<<<dim3(512), dim3(256), 0, stream>>>(Qb, Kb, Vb, xb /* attn_out */);
  gemm_bt<1><<<dim3(32 * 8), dim3(256), 0, stream>>>(xb, wprojT, 1024,
                                                     nullptr, nullptr, nullptr, out, b_proj);
}

// Round 7
// 117.827 us; speedup vs baseline: 1.3840x; 1.0255x over previous
//
#include <hip/hip_runtime.h>
#include <stdint.h>

#define Bn 2
#define Tn 2048
#define Cn 1024
#define Hn 16
#define Dn 64
#define Mn (Bn*Tn)

typedef __attribute__((ext_vector_type(8))) short bf16x8;
typedef __attribute__((ext_vector_type(4))) float f32x4;
typedef __attribute__((ext_vector_type(4))) unsigned int u32x4;
typedef __attribute__((ext_vector_type(2))) unsigned int u32x2;
typedef unsigned short u16;

__device__ __forceinline__ u16 f2bf(float f) {
  union { float f; uint32_t u; } v; v.f = f;
  uint32_t u = v.u;
  return (u16)((u + 0x7fffu + ((u >> 16) & 1u)) >> 16);
}

__device__ __forceinline__ uint32_t pk_bf16(float lo, float hi) {
  uint32_t r;
  asm volatile("v_cvt_pk_bf16_f32 %0, %1, %2" : "=v"(r) : "v"(lo), "v"(hi));
  return r;
}

__device__ __forceinline__ void async16(const void* g, void* lds) {
  __builtin_amdgcn_global_load_lds((const __attribute__((address_space(1))) void*)g,
                                   (__attribute__((address_space(3))) void*)lds,
                                   16, 0, 0);
}

// ---------------- conversion kernels ----------------

__global__ void cvt_x(const float* __restrict__ x, u16* __restrict__ xb) {
  int i = (blockIdx.x * 256 + threadIdx.x) * 4;
  float4 v = *(const float4*)(x + i);
  ushort4 o;
  o.x = f2bf(v.x); o.y = f2bf(v.y); o.z = f2bf(v.z); o.w = f2bf(v.w);
  *(ushort4*)(xb + i) = o;
}

// in: [K][N] f32 row-major  ->  out: [N][K] bf16 row-major (transpose + convert)
template<int K, int N>
__global__ void cvt_T(const float* __restrict__ in, u16* __restrict__ out) {
  __shared__ float tile[32][33];
  int n0 = blockIdx.x * 32, k0 = blockIdx.y * 32;
  int tx = threadIdx.x & 31, ty = threadIdx.x >> 5;  // 32 x 8
  #pragma unroll
  for (int i = 0; i < 32; i += 8)
    tile[ty + i][tx] = in[(size_t)(k0 + ty + i) * N + n0 + tx];
  __syncthreads();
  #pragma unroll
  for (int i = 0; i < 32; i += 8)
    out[(size_t)(n0 + ty + i) * K + k0 + tx] = f2bf(tile[tx][ty + i]);
}

// ---------------- GEMM:  C[M,N] = A[M,K=1024] * Bt[N,K]^T  (bf16 in, f32 acc) ----------------

template<int EPI>
__launch_bounds__(256, 3)
__global__ void gemm_bt(const u16* __restrict__ A, const u16* __restrict__ Bt, int N,
                        u16* __restrict__ Qb, u16* __restrict__ Kb, u16* __restrict__ Vb,
                        float* __restrict__ Out, const float* __restrict__ bias) {
  constexpr int Kd = 1024;
  __shared__ u16 As[128][64];
  __shared__ u16 Bs[128][64];
  const int nT = N >> 7;
  const int cpx = gridDim.x >> 3;
  const int wg = (blockIdx.x & 7) * cpx + (blockIdx.x >> 3);   // XCD-chunked
  const int m0 = (wg / nT) << 7;
  const int n0 = (wg % nT) << 7;
  const int tid = threadIdx.x;
  const int lane = tid & 63, wid = tid >> 6;
  const int wr = wid >> 1, wc = wid & 1;
  const int lr = lane & 15, lg = lane >> 4;

  f32x4 acc[4][4] = {};

  for (int kb = 0; kb < Kd; kb += 64) {
    #pragma unroll
    for (int i = 0; i < 4; ++i) {
      int c = (wid * 4 + i) * 64 + lane;     // chunk id 0..1023
      int row = c >> 3, ko = (c & 7) << 3;
      async16(A + (size_t)(m0 + row) * Kd + kb + ko, &As[0][0] + c * 8);
      async16(Bt + (size_t)(n0 + row) * Kd + kb + ko, &Bs[0][0] + c * 8);
    }
    __syncthreads();
    bf16x8 af[2][4], bf[2][4];
    #pragma unroll
    for (int kc = 0; kc < 2; ++kc) {
      #pragma unroll
      for (int mi = 0; mi < 4; ++mi) {
        af[kc][mi] = *(const bf16x8*)&As[wr * 64 + mi * 16 + lr][kc * 32 + lg * 8];
        bf[kc][mi] = *(const bf16x8*)&Bs[wc * 64 + mi * 16 + lr][kc * 32 + lg * 8];
      }
    }
    #pragma unroll
    for (int kc = 0; kc < 2; ++kc)
      #pragma unroll
      for (int mi = 0; mi < 4; ++mi)
        #pragma unroll
        for (int ni = 0; ni < 4; ++ni)
          acc[mi][ni] = __builtin_amdgcn_mfma_f32_16x16x32_bf16(af[kc][mi], bf[kc][ni], acc[mi][ni], 0, 0, 0);
    __syncthreads();
  }

  if constexpr (EPI == 0) {
    #pragma unroll
    for (int mi = 0; mi < 4; ++mi) {
      int r0 = m0 + wr * 64 + mi * 16 + lg * 4;   // 4 consecutive rows
      int bb = r0 >> 11;
      int t0 = r0 & 2047;
      #pragma unroll
      for (int ni = 0; ni < 4; ++ni) {
        int col = n0 + wc * 64 + ni * 16 + lr;
        int sel = col >> 10, rem = col & 1023;
        int h = rem >> 6, d = rem & 63;
        f32x4 v = acc[mi][ni];
        if (sel == 0) {
          size_t base = ((size_t)(bb * Hn + h) * Tn + t0) * Dn + d;
          #pragma unroll
          for (int r = 0; r < 4; ++r) Qb[base + (size_t)r * Dn] = f2bf(v[r] * 0.125f);
        } else if (sel == 1) {
          size_t base = ((size_t)(bb * Hn + h) * Tn + t0) * Dn + d;
          #pragma unroll
          for (int r = 0; r < 4; ++r) Kb[base + (size_t)r * Dn] = f2bf(v[r]);
        } else {
          size_t base = ((size_t)(bb * Hn + h) * Dn + d) * Tn + t0;
          ushort4 o;
          o.x = f2bf(v[0]); o.y = f2bf(v[1]); o.z = f2bf(v[2]); o.w = f2bf(v[3]);
          *(ushort4*)(Vb + base) = o;
        }
      }
    }
  } else {
    #pragma unroll
    for (int mi = 0; mi < 4; ++mi) {
      int r0 = m0 + wr * 64 + mi * 16 + lg * 4;
      #pragma unroll
      for (int ni = 0; ni < 4; ++ni) {
        int col = n0 + wc * 64 + ni * 16 + lr;
        float bv = bias[col];
        #pragma unroll
        for (int r = 0; r < 4; ++r)
          Out[(size_t)(r0 + r) * Cn + col] = acc[mi][ni][r] + bv;
      }
    }
  }
}

// ---------------- flash attention v5 -------------------------------------------
// Round-4 proven inner loop, single q-tile per block.
// grid: 1024 blocks = 8 XCD x (4 bh-local x 32 q-tiles longest-first).
// 3 blocks/CU resident (LDS 41KB x3 = 123KB) -> 12 waves/CU to cover the
// per-block barrier drains with other blocks' compute.
// S computed as mfma(K,Q): lane holds S[k = f*16+lg*4+r][q = lr].
// PV computed as mfma(V^T, P): O^T[dv = f*16+lg*4+r][q = lr].

__device__ __forceinline__ void stage_kv(const u16* __restrict__ K,
                                         const u16* __restrict__ Vt, int k0,
                                         u16* __restrict__ Kbuf, u16* __restrict__ Vbuf,
                                         int tid) {
  #pragma unroll
  for (int i = 0; i < 2; ++i) {
    int c = i * 256 + tid;            // chunk 0..511 (16 B each)
    int row = c >> 3;
    int js = (c & 7) ^ (row & 7);     // inverse-swizzled source chunk
    async16(K + (size_t)(k0 + row) * Dn + js * 8, Kbuf + c * 8);
    async16(Vt + (size_t)row * Tn + k0 + js * 8, Vbuf + c * 8);
  }
}

__launch_bounds__(256, 3)
__global__ void attn(const u16* __restrict__ Qb, const u16* __restrict__ Kb,
                     const u16* __restrict__ Vb, u16* __restrict__ Ob) {
  __shared__ u16 __attribute__((aligned(16))) Ks[2 * 4096];
  __shared__ u16 __attribute__((aligned(16))) Vs[2 * 4096];
  __shared__ uint32_t __attribute__((aligned(16))) P32[4][16][36]; // per-wave [q][d or k]

  const int raw = blockIdx.x;
  const int xcd = raw & 7;
  const int idx = raw >> 3;                 // 0..127
  const int bh  = xcd * 4 + (idx & 3);      // 4 heads per XCD -> L2 locality
  const int qt  = 31 - (idx >> 2);          // longest q-tiles dispatched first
  const int q0  = qt * 64;
  const int nt  = qt + 1;

  const int tid = threadIdx.x;
  const int lane = tid & 63, wid = tid >> 6;
  const int lr = lane & 15, lg = lane >> 4;
  const int bb = bh >> 4, h = bh & 15;

  const u16* Q  = Qb + (size_t)bh * Tn * Dn;
  const u16* K  = Kb + (size_t)bh * Tn * Dn;
  const u16* Vt = Vb + (size_t)bh * Dn * Tn;

  const int swz = (lr & 7);           // read-side XOR key for K/V tiles
  const int qoff = wid * 16 + lr;     // q offset within 64-row q-tile
  const int koff0 = lg * 4;           // k offset base for this lane

  // Q fragments (B operand): rows q0 + qoff
  bf16x8 qf[2];
  qf[0] = *(const bf16x8*)(Q + (size_t)(q0 + qoff) * Dn + lg * 8);
  qf[1] = *(const bf16x8*)(Q + (size_t)(q0 + qoff) * Dn + 32 + lg * 8);

  f32x4 o[4] = {};                    // O^T: o[f][r] = O[dv=f*16+lg*4+r][q=lr]
  float m = -1e30f, l = 0.f;

  int cur = 0;
  stage_kv(K, Vt, 0, Ks, Vs, tid);
  __syncthreads();

  for (int t = 0; t < nt; ++t) {
    if (t + 1 < nt)
      stage_kv(K, Vt, (t + 1) << 6,
               Ks + (cur ^ 1) * 4096, Vs + (cur ^ 1) * 4096, tid);

    const u16* Kc = Ks + cur * 4096;
    const u16* Vc = Vs + cur * 4096;

    // S^T = K Q^T : s[f][r] = S[k = f*16+lg*4+r][q = lr]
    f32x4 s[4] = {};
    __builtin_amdgcn_s_setprio(1);
    #pragma unroll
    for (int f = 0; f < 4; ++f) {
      const int row = f * 16 + lr;
      #pragma unroll
      for (int kc = 0; kc < 2; ++kc) {
        bf16x8 kf = *(const bf16x8*)(Kc + row * 64 + (((kc * 4 + lg) ^ swz) * 8));
        s[f] = __builtin_amdgcn_mfma_f32_16x16x32_bf16(kf, qf[kc], s[f], 0, 0, 0);
      }
    }
    __builtin_amdgcn_s_setprio(0);

    if (t == nt - 1) {               // diagonal tile: mask k > q
      #pragma unroll
      for (int f = 0; f < 4; ++f)
        #pragma unroll
        for (int r = 0; r < 4; ++r)
          if (f * 16 + koff0 + r > qoff) s[f][r] = -1e30f;
    }

    // per-lane row max over 16 k values, then across the 4 lg groups
    float pm = fmaxf(fmaxf(fmaxf(s[0][0], s[0][1]), fmaxf(s[0][2], s[0][3])),
                     fmaxf(fmaxf(s[1][0], s[1][1]), fmaxf(s[1][2], s[1][3])));
    float pm2 = fmaxf(fmaxf(fmaxf(s[2][0], s[2][1]), fmaxf(s[2][2], s[2][3])),
                      fmaxf(fmaxf(s[3][0], s[3][1]), fmaxf(s[3][2], s[3][3])));
    pm = fmaxf(pm, pm2);
    pm = fmaxf(pm, __shfl_xor(pm, 16));
    pm = fmaxf(pm, __shfl_xor(pm, 32));

    // defer-max: only rescale when the max grew by more than THR=8
    if (!__all(pm - m <= 8.f)) {
      float mn = fmaxf(m, pm);
      float fac = __expf(m - mn);
      l *= fac;
      #pragma unroll
      for (int f = 0; f < 4; ++f) {
        o[f][0] *= fac; o[f][1] *= fac; o[f][2] *= fac; o[f][3] *= fac;
      }
      m = mn;
    }

    float sum = 0.f;
    #pragma unroll
    for (int f = 0; f < 4; ++f) {
      #pragma unroll
      for (int r = 0; r < 4; ++r) {
        float p = __expf(s[f][r] - m);
        s[f][r] = p;
        sum += p;
      }
    }
    sum += __shfl_xor(sum, 16);
    sum += __shfl_xor(sum, 32);
    l += sum;

    // P -> per-wave LDS [q][k], packed b64 writes (4 consecutive k per lane)
    #pragma unroll
    for (int f = 0; f < 4; ++f) {
      u32x2 w;
      w.x = pk_bf16(s[f][0], s[f][1]);
      w.y = pk_bf16(s[f][2], s[f][3]);
      *(u32x2*)&P32[wid][lr][f * 8 + lg * 2] = w;   // u16 offset f*16+lg*4
    }

    // O^T += V^T P : A = V^T fragment (dv rows), B = P fragment ([k][q])
    __builtin_amdgcn_s_setprio(1);
    #pragma unroll
    for (int kc = 0; kc < 2; ++kc) {
      u32x4 p4 = *(const u32x4*)&P32[wid][lr][kc * 16 + lg * 4]; // u16 off kc*32+lg*8
      bf16x8 pf = __builtin_bit_cast(bf16x8, p4);
      #pragma unroll
      for (int f = 0; f < 4; ++f) {
        const int row = f * 16 + lr;
        bf16x8 vf = *(const bf16x8*)(Vc + row * 64 + (((kc * 4 + lg) ^ swz) * 8));
        o[f] = __builtin_amdgcn_mfma_f32_16x16x32_bf16(vf, pf, o[f], 0, 0, 0);
      }
    }
    __builtin_amdgcn_s_setprio(0);

    __syncthreads();                 // drains vmcnt (stage t+1) + LDS reads done
    cur ^= 1;
  }

  // normalize, transpose O^T -> O via P32, store full rows to [B*T][C]
  float inv = 1.f / l;
  #pragma unroll
  for (int f = 0; f < 4; ++f) {
    u32x2 w;
    w.x = pk_bf16(o[f][0] * inv, o[f][1] * inv);
    w.y = pk_bf16(o[f][2] * inv, o[f][3] * inv);
    *(u32x2*)&P32[wid][lr][f * 8 + lg * 2] = w;     // P32[q=lr][d = f*16+lg*4..+3]
  }
  // each of the 4 lg-lanes sharing q-row lr stores 16 d-values (2 x 16B)
  u32x4 r0 = *(const u32x4*)&P32[wid][lr][lg * 8];       // d = lg*16 .. +7
  u32x4 r1 = *(const u32x4*)&P32[wid][lr][lg * 8 + 4];   // d = lg*16+8 .. +15
  u16* obase = Ob + ((size_t)(bb * Tn + q0 + qoff)) * Cn + h * Dn + lg * 16;
  *(u32x4*)(obase) = r0;
  *(u32x4*)(obase + 8) = r1;
}

// ---------------- launch ----------------

extern "C" void kernel_launch(void* const* d_in, const int* in_sizes, int n_in,
                              void* d_out, int out_size, void* d_ws, size_t ws_size,
                              hipStream_t stream) {
  const float* x = (const float*)d_in[0];
  const float* w_qkv = (const float*)d_in[1];
  const float* w_proj = (const float*)d_in[2];
  const float* b_proj = (const float*)d_in[3];
  float* out = (float*)d_out;
  char* ws = (char*)d_ws;

  u16* xb     = (u16*)(ws);                       // 8 MB (reused as attn_out after gemm1)
  u16* wqkvT  = (u16*)(ws + (size_t)( 8u << 20)); // 6 MB
  u16* wprojT = (u16*)(ws + (size_t)(14u << 20)); // 2 MB
  u16* Qb     = (u16*)(ws + (size_t)(16u << 20)); // 8 MB
  u16* Kb     = (u16*)(ws + (size_t)(24u << 20)); // 8 MB
  u16* Vb     = (u16*)(ws + (size_t)(32u << 20)); // 8 MB  (total 40 MB)

  cvt_x<<<dim3(4096), dim3(256), 0, stream>>>(x, xb);
  cvt_T<1024, 3072><<<dim3(96, 32), dim3(256), 0, stream>>>(w_qkv, wqkvT);
  cvt_T<1024, 1024><<<dim3(32, 32), dim3(256), 0, stream>>>(w_proj, wprojT);

  gemm_bt<0><<<dim3(32 * 24), dim3(256), 0, stream>>>(xb, wqkvT, 3072,
                                                      Qb, Kb, Vb, nullptr, nullptr);
  attn<<<dim3(1024), dim3(256), 0, stream>>>(Qb, Kb, Vb, xb /* attn_out */);
  gemm_bt<1><<<dim3(32 * 8), dim3(256), 0, stream>>>(xb, wprojT, 1024,
                                                     nullptr, nullptr, nullptr, out, b_proj);
}